// Round 4
// baseline (15199.371 us; speedup 1.0000x reference)
//
#include <hip/hip_runtime.h>

// LSTM autoencoder, B=512 T=512 D=64 H=256 — ALL I/O IS FLOAT32 (confirmed by
// error-value forensics R2/R3: d_out read as f32 words of my bf16 u16 pairs).
// Persistent 64-WG kernel; bf16 MFMA pipeline internally; weights in registers;
// per-batch-group (8 WG, XCD-local) barrier via monotonic agent-scope counters;
// decoder Dense feedback folded into the recurrent weight; outputs projected
// in-step (reversed time index), stored as f32.

#define KPAD 328                 // K padded to 328 (656B rows: 16B-aligned)
#define HBN  131072              // elements per h ping-pong buffer (512*256)

// ws layout (bytes)
#define BT_ENC_OFF  0u           // [1024][KPAD] bf16  (n=gate col, k:0..255=U_enc, 256..319=W_enc)
#define BT_DEC_OFF  671744u      // [1024][KPAD] bf16  folded U_dec + W_out@W_dec
#define BT_WOUT_OFF 1343488u     // [64][KPAD]  bf16  W_out transposed
#define BFOLD_OFF   1385472u     // [1024] f32   folded b_dec + b_out@W_dec
#define BENC_OFF    1389568u     // [1024] f32   b_enc
#define BOUT_OFF    1393664u     // [64]   f32   b_out
#define HB_OFF      1393920u     // [2][512][256] bf16 h ping-pong
#define CNT_OFF     1918208u     // [128] u64 arrival counters (group g at [g*16])

typedef short          bf16x8 __attribute__((ext_vector_type(8)));
typedef unsigned short u16x8  __attribute__((ext_vector_type(8)));
typedef float          f32x4  __attribute__((ext_vector_type(4)));

__device__ __forceinline__ float b2f(unsigned short u) {
  return __uint_as_float(((unsigned int)u) << 16);
}
__device__ __forceinline__ unsigned short f2bf(float f) {
  unsigned int u = __float_as_uint(f);
  u += 0x7FFFu + ((u >> 16) & 1u);          // RNE
  return (unsigned short)(u >> 16);
}
__device__ __forceinline__ float sigm(float x) {
  return 1.0f / (1.0f + __expf(-x));
}
__device__ __forceinline__ float clampf(float v, float lim) {
  return fminf(fmaxf(v, -lim), lim);        // inert guard for correct dynamics
}

// ---------------------------------------------------------------- prep kernel
// All inputs f32. Builds bf16 weight views + folded decoder weights + f32
// biases, zeroes h ping-pong and counters.
__global__ __launch_bounds__(256) void prep_kernel(
    const float* __restrict__ U_enc, const float* __restrict__ W_enc,
    const float* __restrict__ U_dec, const float* __restrict__ W_dec,
    const float* __restrict__ W_out, const float* __restrict__ b_enc,
    const float* __restrict__ b_dec, const float* __restrict__ b_out,
    unsigned char* __restrict__ ws)
{
  int idx = blockIdx.x * 256 + threadIdx.x;
  if (idx < 335872) {                       // Bt_enc
    int n = idx / KPAD, k = idx % KPAD;
    unsigned short v = 0;
    if (k < 256)      v = f2bf(clampf(U_enc[k * 1024 + n], 8.0f));
    else if (k < 320) v = f2bf(clampf(W_enc[(k - 256) * 1024 + n], 8.0f));
    ((unsigned short*)(ws + BT_ENC_OFF))[n * KPAD + k] = v;
  } else if (idx < 671744) {                // Bt_dec = U_dec + W_out @ W_dec (fold)
    int i = idx - 335872;
    int n = i / KPAD, k = i % KPAD;
    unsigned short v = 0;
    if (k < 256) {
      float s = U_dec[k * 1024 + n];
      for (int d = 0; d < 64; ++d)
        s += W_out[k * 64 + d] * W_dec[d * 1024 + n];
      v = f2bf(clampf(s, 16.0f));
    }
    ((unsigned short*)(ws + BT_DEC_OFF))[n * KPAD + k] = v;
  } else if (idx < 672768) {                // bfold = b_dec + b_out @ W_dec
    int n = idx - 671744;
    float s = b_dec[n];
    for (int d = 0; d < 64; ++d) s += b_out[d] * W_dec[d * 1024 + n];
    ((float*)(ws + BFOLD_OFF))[n] = clampf(s, 16.0f);
  } else if (idx < 803840) {                // zero h ping-pong (S_0 = 0)
    ((unsigned int*)(ws + HB_OFF))[idx - 672768] = 0u;
  } else if (idx < 803968) {                // zero arrival counters
    ((unsigned long long*)(ws + CNT_OFF))[idx - 803840] = 0ull;
  } else if (idx < 824960) {                // Bt_wout
    int i = idx - 803968;
    int n = i / KPAD, k = i % KPAD;
    unsigned short v = 0;
    if (k < 256) v = f2bf(clampf(W_out[k * 64 + n], 8.0f));
    ((unsigned short*)(ws + BT_WOUT_OFF))[n * KPAD + k] = v;
  } else if (idx < 825984) {                // b_enc copy (f32)
    int n = idx - 824960;
    ((float*)(ws + BENC_OFF))[n] = clampf(b_enc[n], 16.0f);
  } else if (idx < 826048) {                // b_out copy (f32)
    int n = idx - 825984;
    ((float*)(ws + BOUT_OFF))[n] = clampf(b_out[n], 16.0f);
  }
}

// ------------------------------------------------------------- frag helpers
template <int KST>
__device__ __forceinline__ void load_breg(const unsigned short* __restrict__ bt,
                                          bf16x8 (&B)[4][10], int h0, int q,
                                          int lane15, int lquad)
{
#pragma unroll
  for (int g = 0; g < 4; ++g) {
    int n = g * 256 + h0 + q * 16 + lane15;   // gate-strided columns
#pragma unroll
    for (int kst = 0; kst < KST; ++kst)
      B[g][kst] = *(const bf16x8*)(bt + n * KPAD + kst * 32 + lquad * 8);
  }
}

template <int KST>
__device__ __forceinline__ void run_mfma(const unsigned short* Alds,
                                         const bf16x8 (&B)[4][10],
                                         f32x4 (&acc)[2][4], int mrow0,
                                         int lane15, int lquad)
{
#pragma unroll
  for (int kst = 0; kst < KST; ++kst) {
    bf16x8 a0 = *(const bf16x8*)(Alds + (mrow0 + lane15) * KPAD + kst * 32 + lquad * 8);
    bf16x8 a1 = *(const bf16x8*)(Alds + (mrow0 + 16 + lane15) * KPAD + kst * 32 + lquad * 8);
#pragma unroll
    for (int g = 0; g < 4; ++g) {
      acc[0][g] = __builtin_amdgcn_mfma_f32_16x16x32_bf16(a0, B[g][kst], acc[0][g], 0, 0, 0);
      acc[1][g] = __builtin_amdgcn_mfma_f32_16x16x32_bf16(a1, B[g][kst], acc[1][g], 0, 0, 0);
    }
  }
}

// --------------------------------------------------------- persistent kernel
// 64 WGs: grp = wg&7 (batch group of 64 rows, XCD-local under round-robin
// dispatch), ht = wg>>3 (hidden tile of 32 units).
__global__ __launch_bounds__(256, 1) void lstm_persist(
    const float* __restrict__ enc_in,
    const unsigned short* __restrict__ bt_enc,
    const unsigned short* __restrict__ bt_dec,
    const unsigned short* __restrict__ bt_wout,
    const float* __restrict__ bfold,
    const float* __restrict__ benc,
    const float* __restrict__ bout,
    unsigned short* __restrict__ hb,
    unsigned long long* __restrict__ cnt,
    float* __restrict__ out)
{
  __shared__ unsigned short Alds[64 * KPAD];   // 41984 B: [h | x] tile
  __shared__ unsigned short Wlds[16 * KPAD];   // 10496 B: W_out slice (rows 8..15 = 0)

  const int tid = threadIdx.x;
  const int wg  = blockIdx.x;
  const int grp = wg & 7;                   // XCD-local group
  const int ht  = wg >> 3;
  const int g0  = grp * 64;
  const int h0  = ht * 32;
  const int w   = tid >> 6;
  const int l   = tid & 63;
  const int lane15 = l & 15;
  const int lquad  = l >> 4;
  const int q      = w >> 1;
  const int mrow0  = (w & 1) * 32;
  unsigned long long* cg = cnt + grp * 16;

  // zero-fill Alds once (covers pad cols 320..327)
  for (int c = tid; c < 2624; c += 256) {
    u16x8 z = {0, 0, 0, 0, 0, 0, 0, 0};
    *(u16x8*)(Alds + c * 8) = z;
  }
  // stage W_out slice -> LDS (used only from u>=512)
  for (int c = tid; c < 16 * 41; c += 256) {
    int r = c / 41, ch = c % 41;
    u16x8 v = {0, 0, 0, 0, 0, 0, 0, 0};
    if (r < 8) v = *(const u16x8*)(bt_wout + (ht * 8 + r) * KPAD + ch * 8);
    *(u16x8*)(Wlds + r * KPAD + ch * 8) = v;
  }
  __syncthreads();

  bf16x8 Breg[4][10];                       // weights resident in registers
  load_breg<10>(bt_enc, Breg, h0, q, lane15, lquad);

  float bias[4];
#pragma unroll
  for (int g = 0; g < 4; ++g)
    bias[g] = benc[g * 256 + h0 + q * 16 + lane15];

  const int oc = ht * 8 + lane15;           // projection out column (lane15<8)
  const float bo = (lane15 < 8) ? bout[oc] : 0.0f;

  float cst[2][4] = {};                     // cell state, lane-resident (f32)

  for (int u = 0; u < 1024; ++u) {
    const bool enc = (u < 512);
    if (u == 512) {                         // phase switch: folded decoder weights
      load_breg<8>(bt_dec, Breg, h0, q, lane15, lquad);
#pragma unroll
      for (int g = 0; g < 4; ++g)
        bias[g] = bfold[g * 256 + h0 + q * 16 + lane15];
    }

    // ---- wait for all 8 WGs of this group to finish step u-1 ----
    if (u > 0) {
      if (tid == 0) {
        const unsigned long long tgt = 8ull * (unsigned long long)u;
        while (__hip_atomic_load(cg, __ATOMIC_ACQUIRE, __HIP_MEMORY_SCOPE_AGENT) < tgt) {}
      }
      __syncthreads();
      __threadfence();
    }

    // ---- stage S_u: 64 rows x 64 u64-chunks, coherent agent loads ----
    const unsigned short* hsrc = hb + (u & 1) * HBN;
    for (int c = tid; c < 4096; c += 256) {
      int r = c >> 6, cc = c & 63;
      unsigned long long v = __hip_atomic_load(
          (const unsigned long long*)(hsrc + (g0 + r) * 256 + cc * 4),
          __ATOMIC_RELAXED, __HIP_MEMORY_SCOPE_AGENT);
      *(unsigned long long*)(Alds + r * KPAD + cc * 4) = v;
    }
    if (enc) {                              // x_t: f32 -> bf16 into LDS
      for (int c = tid; c < 1024; c += 256) {
        int r = c >> 4, cc = c & 15;
        f32x4 xv = *(const f32x4*)(enc_in + ((g0 + r) * 512 + u) * 64 + cc * 4);
        unsigned short* dst = Alds + r * KPAD + 256 + cc * 4;
        dst[0] = f2bf(xv[0]); dst[1] = f2bf(xv[1]);
        dst[2] = f2bf(xv[2]); dst[3] = f2bf(xv[3]);
      }
    }
    __syncthreads();

    // ---- project staged state: out[:, 1023-u] = S_u @ W_out + b_out ----
    if (u >= 512) {
      f32x4 pacc = {bo, bo, bo, bo};
#pragma unroll
      for (int kst = 0; kst < 8; ++kst) {
        bf16x8 a  = *(const bf16x8*)(Alds + (w * 16 + lane15) * KPAD + kst * 32 + lquad * 8);
        bf16x8 bw = *(const bf16x8*)(Wlds + lane15 * KPAD + kst * 32 + lquad * 8);
        pacc = __builtin_amdgcn_mfma_f32_16x16x32_bf16(a, bw, pacc, 0, 0, 0);
      }
      const int colt = 1023 - u;
      if (lane15 < 8) {
#pragma unroll
        for (int r = 0; r < 4; ++r) {
          int b = g0 + w * 16 + lquad * 4 + r;
          out[(b * 512 + colt) * 64 + oc] = clampf(pacc[r], 1024.0f);
        }
      }
      if (u == 1023) break;                 // S_1023 projected -> done
    }

    // ---- recurrent GEMM: z = [h|x] @ Wcat + b ----
    f32x4 acc[2][4];
#pragma unroll
    for (int mt = 0; mt < 2; ++mt)
#pragma unroll
      for (int g = 0; g < 4; ++g) {
        f32x4 t = {bias[g], bias[g], bias[g], bias[g]};
        acc[mt][g] = t;
      }
    if (enc) run_mfma<10>(Alds, Breg, acc, mrow0, lane15, lquad);
    else     run_mfma<8>(Alds, Breg, acc, mrow0, lane15, lquad);

    // ---- LSTM cell (i,f,g,o lane-local) + coherent h-tile store ----
    unsigned short* hdst = hb + ((u + 1) & 1) * HBN;
#pragma unroll
    for (int mt = 0; mt < 2; ++mt)
#pragma unroll
      for (int r = 0; r < 4; ++r) {
        float iv = sigm(acc[mt][0][r]);
        float fv = sigm(acc[mt][1][r]);
        float gv = fmaxf(acc[mt][2][r], 0.0f);   // relu cell activation
        float ov = sigm(acc[mt][3][r]);
        float c  = clampf(fv * cst[mt][r] + iv * gv, 64.0f);
        cst[mt][r] = c;
        float h  = clampf(ov * fmaxf(c, 0.0f), 64.0f);   // h = o * relu(c)
        int row  = mrow0 + mt * 16 + lquad * 4 + r;
        __hip_atomic_store(hdst + (g0 + row) * 256 + h0 + q * 16 + lane15,
                           f2bf(h), __ATOMIC_RELAXED, __HIP_MEMORY_SCOPE_AGENT);
      }

    // ---- signal arrival (release) ----
    __threadfence();
    __syncthreads();
    if (tid == 0)
      __hip_atomic_fetch_add(cg, 1ull, __ATOMIC_RELEASE, __HIP_MEMORY_SCOPE_AGENT);
  }
}

// ------------------------------------------------------------------- launch
extern "C" void kernel_launch(void* const* d_in, const int* in_sizes, int n_in,
                              void* d_out, int out_size, void* d_ws, size_t ws_size,
                              hipStream_t stream) {
  const float* enc_in = (const float*)d_in[0];
  // d_in[1] = decoder_inputs: unused by the inference path
  const float* W_enc = (const float*)d_in[2];
  const float* U_enc = (const float*)d_in[3];
  const float* b_enc = (const float*)d_in[4];
  const float* W_dec = (const float*)d_in[5];
  const float* U_dec = (const float*)d_in[6];
  const float* b_dec = (const float*)d_in[7];
  const float* W_out = (const float*)d_in[8];
  const float* b_out = (const float*)d_in[9];
  unsigned char* ws = (unsigned char*)d_ws;

  prep_kernel<<<3227, 256, 0, stream>>>(U_enc, W_enc, U_dec, W_dec, W_out,
                                        b_enc, b_dec, b_out, ws);
  lstm_persist<<<64, 256, 0, stream>>>(
      enc_in,
      (const unsigned short*)(ws + BT_ENC_OFF),
      (const unsigned short*)(ws + BT_DEC_OFF),
      (const unsigned short*)(ws + BT_WOUT_OFF),
      (const float*)(ws + BFOLD_OFF),
      (const float*)(ws + BENC_OFF),
      (const float*)(ws + BOUT_OFF),
      (unsigned short*)(ws + HB_OFF),
      (unsigned long long*)(ws + CNT_OFF),
      (float*)d_out);
}

// Round 5
// 7955.849 us; speedup vs baseline: 1.9105x; 1.9105x over previous
//
#include <hip/hip_runtime.h>

// LSTM autoencoder, B=512 T=512 D=64 H=256 — all I/O float32.
// Persistent 64-WG kernel; bf16 MFMA internally; weights in registers;
// 8 batch-groups x 8 h-tile WGs; group barrier via monotonic agent-scope
// counters; decoder Dense feedback folded into recurrent weight; outputs
// projected in-step (reversed time), f32 stores.
// R5: remove __threadfence() pair (agent fences = whole-L2 inv/wb ops each
// step); ordering now via sc1-atomic h exchange + barrier vmcnt drain before
// the relaxed signal. h stores via LDS repack -> native u64 atomic stores
// (u16 atomic store risked CAS-loop lowering). x-staging hoisted before the
// spin; projection moved after the signal (off critical path).

#define KPAD 328                 // K padded to 328 (656B rows: 16B-aligned)
#define HBN  131072              // elements per h ping-pong buffer (512*256)

// ws layout (bytes)
#define BT_ENC_OFF  0u           // [1024][KPAD] bf16 (n=gate col, k:0..255=U_enc, 256..319=W_enc)
#define BT_DEC_OFF  671744u      // [1024][KPAD] bf16 folded U_dec + W_out@W_dec
#define BT_WOUT_OFF 1343488u     // [64][KPAD]  bf16 W_out transposed
#define BFOLD_OFF   1385472u     // [1024] f32  folded b_dec + b_out@W_dec
#define BENC_OFF    1389568u     // [1024] f32  b_enc
#define BOUT_OFF    1393664u     // [64]   f32  b_out
#define HB_OFF      1393920u     // [2][512][256] bf16 h ping-pong
#define CNT_OFF     1918208u     // [128] u64 arrival counters (group g at [g*16])

typedef short          bf16x8 __attribute__((ext_vector_type(8)));
typedef unsigned short u16x8  __attribute__((ext_vector_type(8)));
typedef float          f32x4  __attribute__((ext_vector_type(4)));

__device__ __forceinline__ float b2f(unsigned short u) {
  return __uint_as_float(((unsigned int)u) << 16);
}
__device__ __forceinline__ unsigned short f2bf(float f) {
  unsigned int u = __float_as_uint(f);
  u += 0x7FFFu + ((u >> 16) & 1u);          // RNE
  return (unsigned short)(u >> 16);
}
__device__ __forceinline__ float sigm(float x) {
  return 1.0f / (1.0f + __expf(-x));
}
__device__ __forceinline__ float clampf(float v, float lim) {
  return fminf(fmaxf(v, -lim), lim);        // inert guard for correct dynamics
}

// ---------------------------------------------------------------- prep kernel
__global__ __launch_bounds__(256) void prep_kernel(
    const float* __restrict__ U_enc, const float* __restrict__ W_enc,
    const float* __restrict__ U_dec, const float* __restrict__ W_dec,
    const float* __restrict__ W_out, const float* __restrict__ b_enc,
    const float* __restrict__ b_dec, const float* __restrict__ b_out,
    unsigned char* __restrict__ ws)
{
  int idx = blockIdx.x * 256 + threadIdx.x;
  if (idx < 335872) {                       // Bt_enc
    int n = idx / KPAD, k = idx % KPAD;
    unsigned short v = 0;
    if (k < 256)      v = f2bf(clampf(U_enc[k * 1024 + n], 8.0f));
    else if (k < 320) v = f2bf(clampf(W_enc[(k - 256) * 1024 + n], 8.0f));
    ((unsigned short*)(ws + BT_ENC_OFF))[n * KPAD + k] = v;
  } else if (idx < 671744) {                // Bt_dec = U_dec + W_out @ W_dec (fold)
    int i = idx - 335872;
    int n = i / KPAD, k = i % KPAD;
    unsigned short v = 0;
    if (k < 256) {
      float s = U_dec[k * 1024 + n];
      for (int d = 0; d < 64; ++d)
        s += W_out[k * 64 + d] * W_dec[d * 1024 + n];
      v = f2bf(clampf(s, 16.0f));
    }
    ((unsigned short*)(ws + BT_DEC_OFF))[n * KPAD + k] = v;
  } else if (idx < 672768) {                // bfold = b_dec + b_out @ W_dec
    int n = idx - 671744;
    float s = b_dec[n];
    for (int d = 0; d < 64; ++d) s += b_out[d] * W_dec[d * 1024 + n];
    ((float*)(ws + BFOLD_OFF))[n] = clampf(s, 16.0f);
  } else if (idx < 803840) {                // zero h ping-pong (S_0 = 0)
    ((unsigned int*)(ws + HB_OFF))[idx - 672768] = 0u;
  } else if (idx < 803968) {                // zero arrival counters
    ((unsigned long long*)(ws + CNT_OFF))[idx - 803840] = 0ull;
  } else if (idx < 824960) {                // Bt_wout
    int i = idx - 803968;
    int n = i / KPAD, k = i % KPAD;
    unsigned short v = 0;
    if (k < 256) v = f2bf(clampf(W_out[k * 64 + n], 8.0f));
    ((unsigned short*)(ws + BT_WOUT_OFF))[n * KPAD + k] = v;
  } else if (idx < 825984) {                // b_enc copy (f32)
    int n = idx - 824960;
    ((float*)(ws + BENC_OFF))[n] = clampf(b_enc[n], 16.0f);
  } else if (idx < 826048) {                // b_out copy (f32)
    int n = idx - 825984;
    ((float*)(ws + BOUT_OFF))[n] = clampf(b_out[n], 16.0f);
  }
}

// ------------------------------------------------------------- frag helpers
template <int KST>
__device__ __forceinline__ void load_breg(const unsigned short* __restrict__ bt,
                                          bf16x8 (&B)[4][10], int h0, int q,
                                          int lane15, int lquad)
{
#pragma unroll
  for (int g = 0; g < 4; ++g) {
    int n = g * 256 + h0 + q * 16 + lane15;   // gate-strided columns
#pragma unroll
    for (int kst = 0; kst < KST; ++kst)
      B[g][kst] = *(const bf16x8*)(bt + n * KPAD + kst * 32 + lquad * 8);
  }
}

template <int KST>
__device__ __forceinline__ void run_mfma(const unsigned short* Alds,
                                         const bf16x8 (&B)[4][10],
                                         f32x4 (&acc)[2][4], int mrow0,
                                         int lane15, int lquad)
{
#pragma unroll
  for (int kst = 0; kst < KST; ++kst) {
    bf16x8 a0 = *(const bf16x8*)(Alds + (mrow0 + lane15) * KPAD + kst * 32 + lquad * 8);
    bf16x8 a1 = *(const bf16x8*)(Alds + (mrow0 + 16 + lane15) * KPAD + kst * 32 + lquad * 8);
#pragma unroll
    for (int g = 0; g < 4; ++g) {
      acc[0][g] = __builtin_amdgcn_mfma_f32_16x16x32_bf16(a0, B[g][kst], acc[0][g], 0, 0, 0);
      acc[1][g] = __builtin_amdgcn_mfma_f32_16x16x32_bf16(a1, B[g][kst], acc[1][g], 0, 0, 0);
    }
  }
}

// --------------------------------------------------------- persistent kernel
// 64 WGs: grp = wg&7 (batch group of 64 rows, XCD-local under round-robin
// dispatch), ht = wg>>3 (hidden tile of 32 units).
__global__ __launch_bounds__(256, 1) void lstm_persist(
    const float* __restrict__ enc_in,
    const unsigned short* __restrict__ bt_enc,
    const unsigned short* __restrict__ bt_dec,
    const unsigned short* __restrict__ bt_wout,
    const float* __restrict__ bfold,
    const float* __restrict__ benc,
    const float* __restrict__ bout,
    unsigned short* __restrict__ hb,
    unsigned long long* __restrict__ cnt,
    float* __restrict__ out)
{
  __shared__ unsigned short Alds[64 * KPAD];       // 41984 B: [h | x] tile
  __shared__ unsigned short Wlds[16 * KPAD];       // 10496 B: W_out slice
  __shared__ unsigned long long HoutU[512];        //  4096 B: h repack (64x32 u16)

  const int tid = threadIdx.x;
  const int wg  = blockIdx.x;
  const int grp = wg & 7;                   // XCD-local group
  const int ht  = wg >> 3;
  const int g0  = grp * 64;
  const int h0  = ht * 32;
  const int w   = tid >> 6;
  const int l   = tid & 63;
  const int lane15 = l & 15;
  const int lquad  = l >> 4;
  const int q      = w >> 1;
  const int mrow0  = (w & 1) * 32;
  unsigned long long* cg = cnt + grp * 16;
  unsigned short* HoutS = (unsigned short*)HoutU;

  // zero-fill Alds once (covers pad cols 320..327)
  for (int c = tid; c < 2624; c += 256) {
    u16x8 z = {0, 0, 0, 0, 0, 0, 0, 0};
    *(u16x8*)(Alds + c * 8) = z;
  }
  // stage W_out slice -> LDS (used only from u>=512)
  for (int c = tid; c < 16 * 41; c += 256) {
    int r = c / 41, ch = c % 41;
    u16x8 v = {0, 0, 0, 0, 0, 0, 0, 0};
    if (r < 8) v = *(const u16x8*)(bt_wout + (ht * 8 + r) * KPAD + ch * 8);
    *(u16x8*)(Wlds + r * KPAD + ch * 8) = v;
  }
  __syncthreads();

  bf16x8 Breg[4][10];                       // weights resident in registers
  load_breg<10>(bt_enc, Breg, h0, q, lane15, lquad);

  float bias[4];
#pragma unroll
  for (int g = 0; g < 4; ++g)
    bias[g] = benc[g * 256 + h0 + q * 16 + lane15];

  const int oc = ht * 8 + lane15;           // projection out column (lane15<8)
  const float bo = (lane15 < 8) ? bout[oc] : 0.0f;

  float cst[2][4] = {};                     // cell state, lane-resident (f32)

  for (int u = 0; u < 1024; ++u) {
    const bool enc = (u < 512);
    if (u == 512) {                         // phase switch: folded decoder weights
      load_breg<8>(bt_dec, Breg, h0, q, lane15, lquad);
#pragma unroll
      for (int g = 0; g < 4; ++g)
        bias[g] = bfold[g * 256 + h0 + q * 16 + lane15];
    }

    // ---- x_t staging (no cross-WG dependency: before the wait) ----
    if (enc) {
      for (int c = tid; c < 1024; c += 256) {
        int r = c >> 4, cc = c & 15;
        f32x4 xv = *(const f32x4*)(enc_in + ((g0 + r) * 512 + u) * 64 + cc * 4);
        unsigned short* dst = Alds + r * KPAD + 256 + cc * 4;
        dst[0] = f2bf(xv[0]); dst[1] = f2bf(xv[1]);
        dst[2] = f2bf(xv[2]); dst[3] = f2bf(xv[3]);
      }
    }

    // ---- wait for all 8 WGs of this group to finish step u-1 ----
    if (u > 0) {
      if (tid == 0) {
        const unsigned long long tgt = 8ull * (unsigned long long)u;
        while (__hip_atomic_load(cg, __ATOMIC_RELAXED, __HIP_MEMORY_SCOPE_AGENT) < tgt) {}
      }
      __syncthreads();                      // no fence: h exchange is sc1-atomic
    }

    // ---- stage S_u: 64 rows x 32 u64-chunks, coherent agent loads ----
    const unsigned short* hsrc = hb + (u & 1) * HBN;
    for (int c = tid; c < 4096; c += 256) {
      int r = c >> 6, cc = c & 63;
      unsigned long long v = __hip_atomic_load(
          (const unsigned long long*)(hsrc + (g0 + r) * 256 + cc * 4),
          __ATOMIC_RELAXED, __HIP_MEMORY_SCOPE_AGENT);
      *(unsigned long long*)(Alds + r * KPAD + cc * 4) = v;
    }
    __syncthreads();

    if (u < 1023) {
      // ---- recurrent GEMM: z = [h|x] @ Wcat + b ----
      f32x4 acc[2][4];
#pragma unroll
      for (int mt = 0; mt < 2; ++mt)
#pragma unroll
        for (int g = 0; g < 4; ++g) {
          f32x4 t = {bias[g], bias[g], bias[g], bias[g]};
          acc[mt][g] = t;
        }
      if (enc) run_mfma<10>(Alds, Breg, acc, mrow0, lane15, lquad);
      else     run_mfma<8>(Alds, Breg, acc, mrow0, lane15, lquad);

      // ---- LSTM cell -> LDS repack buffer ----
#pragma unroll
      for (int mt = 0; mt < 2; ++mt)
#pragma unroll
        for (int r = 0; r < 4; ++r) {
          float iv = sigm(acc[mt][0][r]);
          float fv = sigm(acc[mt][1][r]);
          float gv = fmaxf(acc[mt][2][r], 0.0f);   // relu cell activation
          float ov = sigm(acc[mt][3][r]);
          float c  = clampf(fv * cst[mt][r] + iv * gv, 64.0f);
          cst[mt][r] = c;
          float h  = clampf(ov * fmaxf(c, 0.0f), 64.0f); // h = o * relu(c)
          int row  = mrow0 + mt * 16 + lquad * 4 + r;
          HoutS[row * 32 + q * 16 + lane15] = f2bf(h);
        }
      __syncthreads();                      // Hout complete

      // ---- h-tile -> global: native u64 relaxed agent atomic stores ----
      unsigned short* hdst = hb + ((u + 1) & 1) * HBN;
#pragma unroll
      for (int i = tid; i < 512; i += 256) {
        int row = i >> 3, cch = i & 7;
        __hip_atomic_store(
            (unsigned long long*)(hdst + (g0 + row) * 256 + h0 + cch * 4),
            HoutU[i], __ATOMIC_RELAXED, __HIP_MEMORY_SCOPE_AGENT);
      }
      __builtin_amdgcn_s_waitcnt(0);        // belt: drain this wave's stores
      __syncthreads();                      // all waves' stores drained
      if (tid == 0)                         // signal arrival for step u
        __hip_atomic_fetch_add(cg, 1ull, __ATOMIC_RELAXED, __HIP_MEMORY_SCOPE_AGENT);
    }

    // ---- projection AFTER signal (off critical path): out[:,1023-u] ----
    if (u >= 512) {
      f32x4 pacc = {bo, bo, bo, bo};
#pragma unroll
      for (int kst = 0; kst < 8; ++kst) {
        bf16x8 a  = *(const bf16x8*)(Alds + (w * 16 + lane15) * KPAD + kst * 32 + lquad * 8);
        bf16x8 bw = *(const bf16x8*)(Wlds + lane15 * KPAD + kst * 32 + lquad * 8);
        pacc = __builtin_amdgcn_mfma_f32_16x16x32_bf16(a, bw, pacc, 0, 0, 0);
      }
      const int colt = 1023 - u;
      if (lane15 < 8) {
#pragma unroll
        for (int r = 0; r < 4; ++r) {
          int b = g0 + w * 16 + lquad * 4 + r;
          out[(b * 512 + colt) * 64 + oc] = clampf(pacc[r], 1024.0f);
        }
      }
    }
  }
}

// ------------------------------------------------------------------- launch
extern "C" void kernel_launch(void* const* d_in, const int* in_sizes, int n_in,
                              void* d_out, int out_size, void* d_ws, size_t ws_size,
                              hipStream_t stream) {
  const float* enc_in = (const float*)d_in[0];
  // d_in[1] = decoder_inputs: unused by the inference path
  const float* W_enc = (const float*)d_in[2];
  const float* U_enc = (const float*)d_in[3];
  const float* b_enc = (const float*)d_in[4];
  const float* W_dec = (const float*)d_in[5];
  const float* U_dec = (const float*)d_in[6];
  const float* b_dec = (const float*)d_in[7];
  const float* W_out = (const float*)d_in[8];
  const float* b_out = (const float*)d_in[9];
  unsigned char* ws = (unsigned char*)d_ws;

  prep_kernel<<<3227, 256, 0, stream>>>(U_enc, W_enc, U_dec, W_dec, W_out,
                                        b_enc, b_dec, b_out, ws);
  lstm_persist<<<64, 256, 0, stream>>>(
      enc_in,
      (const unsigned short*)(ws + BT_ENC_OFF),
      (const unsigned short*)(ws + BT_DEC_OFF),
      (const unsigned short*)(ws + BT_WOUT_OFF),
      (const float*)(ws + BFOLD_OFF),
      (const float*)(ws + BENC_OFF),
      (const float*)(ws + BOUT_OFF),
      (unsigned short*)(ws + HB_OFF),
      (unsigned long long*)(ws + CNT_OFF),
      (float*)d_out);
}